// Round 4
// baseline (925.766 us; speedup 1.0000x reference)
//
#include <hip/hip_runtime.h>
#include <math.h>

// ---------------- problem constants ----------------
#define B_ROWS 65536
#define D_IN   512
#define HDIM   512
#define FAN    1024          // D_IN + HDIM
#define NCOL   2048          // 4 gates * HDIM
#define EPS    1e-5f

// GEMM tile
#define BM 128
#define BN 128
#define BK 64
#define KSTEPS (FAN / BK)    // 16

typedef unsigned short u16;
using bfrag = __attribute__((ext_vector_type(8))) short;          // 8 bf16 (4 VGPRs)
using facc  = __attribute__((ext_vector_type(4))) float;          // 4 fp32 acc
using us4   = __attribute__((ext_vector_type(4))) unsigned short;
using us8   = __attribute__((ext_vector_type(8))) unsigned short;

// ---------------- helpers ----------------
static __device__ __forceinline__ u16 f2b(float f) {              // fp32 -> bf16 RNE
    unsigned u = __builtin_bit_cast(unsigned, f);
    u += 0x7fffu + ((u >> 16) & 1u);
    return (u16)(u >> 16);
}
static __device__ __forceinline__ float b2f(u16 h) {
    unsigned u = ((unsigned)h) << 16;
    return __builtin_bit_cast(float, u);
}
static __device__ __forceinline__ void gload16(const u16* g, u16* l) {
    __builtin_amdgcn_global_load_lds(
        (const __attribute__((address_space(1))) void*)g,
        (__attribute__((address_space(3))) void*)l, 16, 0, 0);
}

// Block-wide LayerNorm over 512 values (256 threads x 2 values each).
// torch-style: unbiased std (ddof=1), eps added to std.
static __device__ __forceinline__ void ln_pair(
    float y0, float y1,
    const float* __restrict__ gam, const float* __restrict__ bet, int c0,
    float* red, int lane, int wid, float& o0, float& o1)
{
    float s = y0 + y1, ss = y0 * y0 + y1 * y1;
#pragma unroll
    for (int o = 32; o; o >>= 1) { s += __shfl_down(s, o); ss += __shfl_down(ss, o); }
    if (lane == 0) { red[wid * 2] = s; red[wid * 2 + 1] = ss; }
    __syncthreads();
    float S  = red[0] + red[2] + red[4] + red[6];
    float SS = red[1] + red[3] + red[5] + red[7];
    __syncthreads();
    float mean = S * (1.f / 512.f);
    float var  = (SS - 512.f * mean * mean) * (1.f / 511.f);
    float rstd = 1.f / (sqrtf(fmaxf(var, 0.f)) + EPS);
    o0 = (y0 - mean) * rstd * gam[c0]     + bet[c0];
    o1 = (y1 - mean) * rstd * gam[c0 + 1] + bet[c0 + 1];
}

// ---------------- kernel 0a: pack combined = concat(x, prev_h) as bf16 ----------------
__global__ void pack_combined(const float* __restrict__ x, const float* __restrict__ ph,
                              u16* __restrict__ comb)
{
    long i = (long)blockIdx.x * 256 + threadIdx.x;                 // one float4 of x + one of h
    if (i >= (long)B_ROWS * D_IN / 4) return;
    long e = i * 4;
    long b = e >> 9;                                               // /512
    int  d = (int)(e & 511);
    float4 xv = *(const float4*)(x + e);
    float4 hv = *(const float4*)(ph + e);
    us4 xb = { f2b(xv.x), f2b(xv.y), f2b(xv.z), f2b(xv.w) };
    us4 hb = { f2b(hv.x), f2b(hv.y), f2b(hv.z), f2b(hv.w) };
    *(us4*)(comb + b * FAN + d)        = xb;
    *(us4*)(comb + b * FAN + D_IN + d) = hb;
}

// ---------------- kernel 0b: pack W = [Wf;Wi;Wo;Wj] as bf16 [2048][1024] ----------------
__global__ void pack_w(const float* __restrict__ Wf, const float* __restrict__ Wi,
                       const float* __restrict__ Wo, const float* __restrict__ Wj,
                       u16* __restrict__ Wall)
{
    long i = (long)blockIdx.x * 256 + threadIdx.x;
    if (i >= (long)NCOL * FAN / 4) return;
    long e = i * 4;
    int  g = (int)(e >> 19);                                       // 512*1024 = 2^19 per gate
    long rem = e & 524287L;
    const float* src = (g == 0) ? Wf : (g == 1) ? Wi : (g == 2) ? Wo : Wj;
    float4 v = *(const float4*)(src + rem);
    us4 p = { f2b(v.x), f2b(v.y), f2b(v.z), f2b(v.w) };
    *(us4*)(Wall + e) = p;
}

// ---------------- kernel 1: GEMM  Cg[M,2048] = A[M,1024] * W[2048,1024]^T (bf16 in/out, fp32 acc)
__global__ __launch_bounds__(256, 2)
void gemm_gates(const u16* __restrict__ A, const u16* __restrict__ W, u16* __restrict__ Cg)
{
    __shared__ u16 ldsA[2][BM * BK];   // 2 x 16 KB
    __shared__ u16 ldsB[2][BN * BK];   // 2 x 16 KB

    const int tid  = threadIdx.x;
    const int lane = tid & 63;
    const int wid  = tid >> 6;         // 4 waves, 2x2
    const int wm   = wid >> 1;
    const int wn   = wid & 1;
    const int  bn  = blockIdx.x & 15;  // NCOL/BN = 16, n-fastest for A-panel L2/L3 reuse
    const long bm  = blockIdx.x >> 4;
    const long arow0 = bm * BM;
    const long brow0 = (long)bn * BN;
    const int srow = lane >> 3;        // staging: 8 rows per 1KB chunk
    const int scol = (lane & 7) * 8;

    facc acc[4][4];
#pragma unroll
    for (int i = 0; i < 4; ++i)
#pragma unroll
        for (int j = 0; j < 4; ++j) acc[i][j] = facc{0.f, 0.f, 0.f, 0.f};

    auto stage = [&](int buf, int k0) {
#pragma unroll
        for (int i = 0; i < 4; ++i) {
            const int c = wid * 4 + i;             // chunk 0..15, 1KB each (linear LDS fill)
            const int r = c * 8 + srow;
            gload16(A + (arow0 + r) * FAN + k0 + scol, &ldsA[buf][c * 512]);
            gload16(W + (brow0 + r) * FAN + k0 + scol, &ldsB[buf][c * 512]);
        }
    };

    stage(0, 0);
    __syncthreads();                               // drains vmcnt before barrier

    const int arbase = (wm * 64 + (lane & 15)) * BK;
    const int brbase = (wn * 64 + (lane & 15)) * BK;
    const int koff   = (lane >> 4) * 8;

    for (int kt = 0; kt < KSTEPS; ++kt) {
        const int cur = kt & 1;
        if (kt + 1 < KSTEPS) stage(cur ^ 1, (kt + 1) * BK);
        const u16* As = ldsA[cur];
        const u16* Bs = ldsB[cur];
#pragma unroll
        for (int kk = 0; kk < 2; ++kk) {
            bfrag av[4], bv[4];
#pragma unroll
            for (int f = 0; f < 4; ++f)
                av[f] = *(const bfrag*)(As + arbase + f * 16 * BK + kk * 32 + koff);
#pragma unroll
            for (int f = 0; f < 4; ++f)
                bv[f] = *(const bfrag*)(Bs + brbase + f * 16 * BK + kk * 32 + koff);
#pragma unroll
            for (int i = 0; i < 4; ++i)
#pragma unroll
                for (int j = 0; j < 4; ++j)
                    acc[i][j] = __builtin_amdgcn_mfma_f32_16x16x32_bf16(av[i], bv[j], acc[i][j], 0, 0, 0);
        }
        __syncthreads();
    }

    // epilogue: restage C-tile (bf16) through LDS for coalesced 16B stores
    u16* ct = (u16*)ldsA;                          // 16384 u16 = 128x128, aliases both bufs
#pragma unroll
    for (int i = 0; i < 4; ++i)
#pragma unroll
        for (int j = 0; j < 4; ++j) {
            const int row = wm * 64 + i * 16 + ((lane >> 4) << 2);   // C/D: row=(lane>>4)*4+reg
            const int col = wn * 64 + j * 16 + (lane & 15);          //      col=lane&15
#pragma unroll
            for (int r = 0; r < 4; ++r)
                ct[(row + r) * BN + col] = f2b(acc[i][j][r]);
        }
    __syncthreads();
#pragma unroll
    for (int it = 0; it < 8; ++it) {
        const int ch  = it * 256 + tid;            // 2048 chunks of 8 elems
        const int row = ch >> 4;
        const int col = (ch & 15) * 8;
        *(us8*)(Cg + (arow0 + row) * NCOL + brow0 + col) = *(const us8*)(ct + row * BN + col);
    }
}

// ---------------- kernel 2: per-row LN + activations + cell update ----------------
__global__ __launch_bounds__(256)
void lstm_epilogue(const u16* __restrict__ pre, const float* __restrict__ pc,
                   const float* __restrict__ bf_, const float* __restrict__ bi_,
                   const float* __restrict__ bo_, const float* __restrict__ bj_,
                   const float* __restrict__ gf, const float* __restrict__ btf,
                   const float* __restrict__ gi, const float* __restrict__ bti,
                   const float* __restrict__ go, const float* __restrict__ bto,
                   const float* __restrict__ gj, const float* __restrict__ btj,
                   const float* __restrict__ gc, const float* __restrict__ btc,
                   float* __restrict__ out_h, float* __restrict__ out_c)
{
    __shared__ float red[8];
    const int b = blockIdx.x, t = threadIdx.x;
    const int lane = t & 63, wid = t >> 6;
    const int c0 = t * 2;

    const float* bs[4]  = { bf_, bi_, bo_, bj_ };
    const float* gs[4]  = { gf, gi, go, gj };
    const float* bts[4] = { btf, bti, bto, btj };

    float a[4][2];
#pragma unroll
    for (int g = 0; g < 4; ++g) {
        unsigned pv = *(const unsigned*)(pre + (long)b * NCOL + g * HDIM + c0);
        float y0 = b2f((u16)(pv & 0xffffu)) + bs[g][c0];
        float y1 = b2f((u16)(pv >> 16))     + bs[g][c0 + 1];
        ln_pair(y0, y1, gs[g], bts[g], c0, red, lane, wid, a[g][0], a[g][1]);
        if (g == 3) { a[g][0] = tanhf(a[g][0]); a[g][1] = tanhf(a[g][1]); }
        else        { a[g][0] = 1.f / (1.f + expf(-a[g][0]));
                      a[g][1] = 1.f / (1.f + expf(-a[g][1])); }
    }
    float2 pcv = *(const float2*)(pc + (long)b * HDIM + c0);
    float f0 = a[0][0], i0 = a[1][0], o0 = a[2][0], j0 = a[3][0];
    float f1 = a[0][1], i1 = a[1][1], o1 = a[2][1], j1 = a[3][1];
    float cr0 = f0 * pcv.x + fminf(1.f - f0, i0) * j0;
    float cr1 = f1 * pcv.y + fminf(1.f - f1, i1) * j1;
    float cc0, cc1;
    ln_pair(cr0, cr1, gc, btc, c0, red, lane, wid, cc0, cc1);
    *(float2*)(out_h + (long)b * HDIM + c0) = make_float2(o0 * cc0, o1 * cc1);
    *(float2*)(out_c + (long)b * HDIM + c0) = make_float2(cc0, cc1);
}

// ---------------- fallback (only if ws too small): fp32 naive, no workspace ----------------
__global__ __launch_bounds__(256)
void lstm_naive(const float* __restrict__ x, const float* __restrict__ ph, const float* __restrict__ pc,
                const float* __restrict__ Wf, const float* __restrict__ bf_,
                const float* __restrict__ Wi, const float* __restrict__ bi_,
                const float* __restrict__ Wo, const float* __restrict__ bo_,
                const float* __restrict__ Wj, const float* __restrict__ bj_,
                const float* __restrict__ gf, const float* __restrict__ btf,
                const float* __restrict__ gi, const float* __restrict__ bti,
                const float* __restrict__ go, const float* __restrict__ bto,
                const float* __restrict__ gj, const float* __restrict__ btj,
                const float* __restrict__ gc, const float* __restrict__ btc,
                float* __restrict__ out_h, float* __restrict__ out_c)
{
    __shared__ float comb[FAN];
    __shared__ float red[8];
    const int b = blockIdx.x, t = threadIdx.x;
    const int lane = t & 63, wid = t >> 6;
    for (int k = t; k < D_IN; k += 256) {
        comb[k]        = x[(long)b * D_IN + k];
        comb[D_IN + k] = ph[(long)b * HDIM + k];
    }
    __syncthreads();
    const int c0 = t * 2;
    const float* Ws[4]  = { Wf, Wi, Wo, Wj };
    const float* bs[4]  = { bf_, bi_, bo_, bj_ };
    const float* gs[4]  = { gf, gi, go, gj };
    const float* bts[4] = { btf, bti, bto, btj };
    float a[4][2];
#pragma unroll
    for (int g = 0; g < 4; ++g) {
        float y[2];
#pragma unroll
        for (int e = 0; e < 2; ++e) {
            const float4* w4 = (const float4*)(Ws[g] + (long)(c0 + e) * FAN);
            const float4* c4 = (const float4*)comb;
            float s = 0.f;
            for (int k = 0; k < FAN / 4; ++k) {
                float4 wv = w4[k], cv = c4[k];
                s += wv.x * cv.x + wv.y * cv.y + wv.z * cv.z + wv.w * cv.w;
            }
            y[e] = s + bs[g][c0 + e];
        }
        ln_pair(y[0], y[1], gs[g], bts[g], c0, red, lane, wid, a[g][0], a[g][1]);
        if (g == 3) { a[g][0] = tanhf(a[g][0]); a[g][1] = tanhf(a[g][1]); }
        else        { a[g][0] = 1.f / (1.f + expf(-a[g][0]));
                      a[g][1] = 1.f / (1.f + expf(-a[g][1])); }
    }
    float2 pcv = *(const float2*)(pc + (long)b * HDIM + c0);
    float f0 = a[0][0], i0 = a[1][0], o0 = a[2][0], j0 = a[3][0];
    float f1 = a[0][1], i1 = a[1][1], o1 = a[2][1], j1 = a[3][1];
    float cr0 = f0 * pcv.x + fminf(1.f - f0, i0) * j0;
    float cr1 = f1 * pcv.y + fminf(1.f - f1, i1) * j1;
    float cc0, cc1;
    ln_pair(cr0, cr1, gc, btc, c0, red, lane, wid, cc0, cc1);
    *(float2*)(out_h + (long)b * HDIM + c0) = make_float2(o0 * cc0, o1 * cc1);
    *(float2*)(out_c + (long)b * HDIM + c0) = make_float2(cc0, cc1);
}

// ---------------- launcher ----------------
extern "C" void kernel_launch(void* const* d_in, const int* in_sizes, int n_in,
                              void* d_out, int out_size, void* d_ws, size_t ws_size,
                              hipStream_t stream)
{
    const float* x   = (const float*)d_in[0];
    const float* ph  = (const float*)d_in[1];
    const float* pc  = (const float*)d_in[2];
    const float* Wf  = (const float*)d_in[3];
    const float* bf_ = (const float*)d_in[4];
    const float* Wi  = (const float*)d_in[5];
    const float* bi_ = (const float*)d_in[6];
    const float* Wo  = (const float*)d_in[7];
    const float* bo_ = (const float*)d_in[8];
    const float* Wj  = (const float*)d_in[9];
    const float* bj_ = (const float*)d_in[10];
    const float* gf  = (const float*)d_in[11];
    const float* btf = (const float*)d_in[12];
    const float* gi  = (const float*)d_in[13];
    const float* bti = (const float*)d_in[14];
    const float* go  = (const float*)d_in[15];
    const float* bto = (const float*)d_in[16];
    const float* gj  = (const float*)d_in[17];
    const float* btj = (const float*)d_in[18];
    const float* gc  = (const float*)d_in[19];
    const float* btc = (const float*)d_in[20];
    float* out_h = (float*)d_out;
    float* out_c = out_h + (size_t)B_ROWS * HDIM;

    const size_t combElems  = (size_t)B_ROWS * FAN;        // 128 MiB bf16
    const size_t wElems     = (size_t)NCOL * FAN;          //   4 MiB bf16
    const size_t fixedBytes = (combElems + wElems) * 2;

    long slabRows = 0;
    if (ws_size > fixedBytes) {
        size_t avail = ws_size - fixedBytes;
        slabRows = (long)(avail / ((size_t)NCOL * 2));      // bf16 preact bytes per row
        slabRows &= ~127L;                                  // multiple of BM
        if (slabRows > B_ROWS) slabRows = B_ROWS;
    }

    if (slabRows >= 128) {
        u16* comb = (u16*)d_ws;
        u16* Wall = comb + combElems;
        u16* pre  = Wall + wElems;
        pack_combined<<<dim3((unsigned)((B_ROWS * (long)D_IN / 4 + 255) / 256)), dim3(256), 0, stream>>>(x, ph, comb);
        pack_w<<<dim3((unsigned)(((long)NCOL * FAN / 4 + 255) / 256)), dim3(256), 0, stream>>>(Wf, Wi, Wo, Wj, Wall);
        for (long r0 = 0; r0 < B_ROWS; r0 += slabRows) {
            long rows = B_ROWS - r0; if (rows > slabRows) rows = slabRows;
            gemm_gates<<<dim3((unsigned)((rows / BM) * (NCOL / BN))), dim3(256), 0, stream>>>(
                comb + r0 * FAN, Wall, pre);
            lstm_epilogue<<<dim3((unsigned)rows), dim3(256), 0, stream>>>(
                pre, pc + r0 * HDIM,
                bf_, bi_, bo_, bj_,
                gf, btf, gi, bti, go, bto, gj, btj, gc, btc,
                out_h + r0 * HDIM, out_c + r0 * HDIM);
        }
    } else {
        lstm_naive<<<dim3(B_ROWS), dim3(256), 0, stream>>>(
            x, ph, pc, Wf, bf_, Wi, bi_, Wo, bo_, Wj, bj_,
            gf, btf, gi, bti, go, bto, gj, btj, gc, btc, out_h, out_c);
    }
}

// Round 5
// 523.237 us; speedup vs baseline: 1.7693x; 1.7693x over previous
//
#include <hip/hip_runtime.h>
#include <math.h>

// ---------------- problem constants ----------------
#define B_ROWS 65536
#define D_IN   512
#define HDIM   512
#define FAN    1024          // D_IN + HDIM
#define NCOL   2048          // 4 gates * HDIM
#define EPS    1e-5f

// GEMM tile (256^2 8-phase template, m201-style)
#define BM 256
#define BN 256
#define BK 64
#define KTILES (FAN / BK)    // 16
#define NITER  (KTILES / 2)  // 8 iterations, 2 K-tiles each

typedef unsigned short u16;
using bfrag = __attribute__((ext_vector_type(8))) short;          // 8 bf16 (4 VGPRs)
using facc  = __attribute__((ext_vector_type(4))) float;          // 4 fp32 acc
using us4   = __attribute__((ext_vector_type(4))) unsigned short;
using us8   = __attribute__((ext_vector_type(8))) unsigned short;

// ---------------- helpers ----------------
static __device__ __forceinline__ u16 f2b(float f) {              // fp32 -> bf16 RNE
    unsigned u = __builtin_bit_cast(unsigned, f);
    u += 0x7fffu + ((u >> 16) & 1u);
    return (u16)(u >> 16);
}
static __device__ __forceinline__ float b2f(u16 h) {
    unsigned u = ((unsigned)h) << 16;
    return __builtin_bit_cast(float, u);
}
static __device__ __forceinline__ void gload16(const u16* g, u16* l) {
    __builtin_amdgcn_global_load_lds(
        (const __attribute__((address_space(1))) void*)g,
        (__attribute__((address_space(3))) void*)l, 16, 0, 0);
}

// ---------------- kernel 0a: pack combined = concat(x, prev_h) as bf16 ----------------
__global__ void pack_combined(const float* __restrict__ x, const float* __restrict__ ph,
                              u16* __restrict__ comb)
{
    long i = (long)blockIdx.x * 256 + threadIdx.x;
    if (i >= (long)B_ROWS * D_IN / 4) return;
    long e = i * 4;
    long b = e >> 9;
    int  d = (int)(e & 511);
    float4 xv = *(const float4*)(x + e);
    float4 hv = *(const float4*)(ph + e);
    us4 xb = { f2b(xv.x), f2b(xv.y), f2b(xv.z), f2b(xv.w) };
    us4 hb = { f2b(hv.x), f2b(hv.y), f2b(hv.z), f2b(hv.w) };
    *(us4*)(comb + b * FAN + d)        = xb;
    *(us4*)(comb + b * FAN + D_IN + d) = hb;
}

// ---------------- kernel 0b: pack W = [Wf;Wi;Wo;Wj] as bf16 [2048][1024] ----------------
__global__ void pack_w(const float* __restrict__ Wf, const float* __restrict__ Wi,
                       const float* __restrict__ Wo, const float* __restrict__ Wj,
                       u16* __restrict__ Wall)
{
    long i = (long)blockIdx.x * 256 + threadIdx.x;
    if (i >= (long)NCOL * FAN / 4) return;
    long e = i * 4;
    int  g = (int)(e >> 19);
    long rem = e & 524287L;
    const float* src = (g == 0) ? Wf : (g == 1) ? Wi : (g == 2) ? Wo : Wj;
    float4 v = *(const float4*)(src + rem);
    us4 p = { f2b(v.x), f2b(v.y), f2b(v.z), f2b(v.w) };
    *(us4*)(Wall + e) = p;
}

// ---------------- kernel 1: 256^2 8-phase GEMM  Cg = A[M,1024] * W[2048,1024]^T ----------
// 512 threads = 8 waves (2M x 4N); per-wave output 128x64; acc[8][4] f32x4.
// LDS: 2 buffers x 4 halves (A-lo, A-hi, B-lo, B-hi) x 128x64 bf16 = 128 KiB.
// buf0 holds even K-tiles, buf1 odd. Slot-XOR swizzle (slot ^= row&7) applied via
// inverse-swizzled global source (linear global_load_lds dest) + swizzled ds_read.
__global__ __launch_bounds__(512)
void gemm_gates(const u16* __restrict__ A, const u16* __restrict__ W, u16* __restrict__ Cg)
{
    __shared__ u16 lds[2][4][8192];

    const int tid  = threadIdx.x;
    const int lane = tid & 63;
    const int wid  = tid >> 6;
    const int wm   = wid >> 2;         // 0..1
    const int wn   = wid & 3;          // 0..3

    // XCD-aware swizzle (nwg % 8 == 0 always: NCOL/BN = 8)
    const int nwg = gridDim.x;
    const int wg  = (blockIdx.x & 7) * (nwg >> 3) + (blockIdx.x >> 3);
    const long bm = wg >> 3;
    const int  bn = wg & 7;
    const long arow0 = bm * BM;
    const long bcol0 = (long)bn * BN;

    const int sr = tid >> 3;           // staging row within half (i adds 64)
    const int ss = tid & 7;            // linear 16B slot

    facc acc[8][4];
#pragma unroll
    for (int i = 0; i < 8; ++i)
#pragma unroll
        for (int j = 0; j < 4; ++j) acc[i][j] = facc{0.f, 0.f, 0.f, 0.f};

    auto stageHalf = [&](int buf, int half, int kt) {
        const long k0 = (long)kt * BK;
#pragma unroll
        for (int i = 0; i < 2; ++i) {
            const int r  = sr + i * 64;
            const int sx = ss ^ (r & 7);                    // inverse swizzle on source
            const u16* src = (half < 2)
                ? (A + (arow0 + half * 128 + r) * (long)FAN + k0 + sx * 8)
                : (W + (bcol0 + (half - 2) * 128 + r) * (long)FAN + k0 + sx * 8);
            gload16(src, &lds[buf][half][i * 4096 + wid * 512]);
        }
    };

    // prologue: K-tile 0 (all 4 halves) -> buf0; K-tile 1 B-halves -> buf1.
    stageHalf(0, 0, 0); stageHalf(0, 1, 0); stageHalf(0, 2, 0); stageHalf(0, 3, 0);
    stageHalf(1, 2, 1); stageHalf(1, 3, 1);
    asm volatile("s_waitcnt vmcnt(4)" ::: "memory");        // tile0 halves complete
    __builtin_amdgcn_s_barrier();

    const u16* Ah[2] = { &lds[0][wm][0],            &lds[1][wm][0] };
    const u16* Bh[2] = { &lds[0][2 + (wn >> 1)][0], &lds[1][2 + (wn >> 1)][0] };
    const int lrB0 = (wn & 1) * 64;

#pragma unroll 1
    for (int t = 0; t < NITER; ++t) {
        const bool pf = (t + 1 < NITER);
        bfrag bq[4][2];
#pragma unroll
        for (int p = 0; p < 8; ++p) {
            const int q  = p & 3;
            const int lt = p >> 2;
            bfrag aq[2][2];
            if (q == 0) {                                   // B-frags once per K-tile
#pragma unroll
                for (int nf = 0; nf < 4; ++nf)
#pragma unroll
                    for (int kk = 0; kk < 2; ++kk) {
                        const int lr = lrB0 + nf * 16 + (lane & 15);
                        const int sl = (kk * 4 + (lane >> 4)) ^ (lane & 7);
                        bq[nf][kk] = *(const bfrag*)(Bh[lt] + lr * 64 + sl * 8);
                    }
            }
#pragma unroll
            for (int m2 = 0; m2 < 2; ++m2)                  // A quadrant (2 M-frags)
#pragma unroll
                for (int kk = 0; kk < 2; ++kk) {
                    const int lr = (q * 2 + m2) * 16 + (lane & 15);
                    const int sl = (kk * 4 + (lane >> 4)) ^ (lane & 7);
                    aq[m2][kk] = *(const bfrag*)(Ah[lt] + lr * 64 + sl * 8);
                }
            // staging schedule: each half staged the phase after its last reader.
            if (p == 0)      stageHalf(1, 0, 2 * t + 1);
            else if (p == 1) stageHalf(1, 1, 2 * t + 1);
            else if (p == 2) { if (pf) stageHalf(0, 2, 2 * t + 2); }
            else if (p == 3) { if (pf) stageHalf(0, 3, 2 * t + 2); }
            else if (p == 4) { if (pf) stageHalf(0, 0, 2 * t + 2); }
            else if (p == 5) { if (pf) stageHalf(0, 1, 2 * t + 2); }
            else if (p == 6) { if (pf) stageHalf(1, 2, 2 * t + 3); }
            else             { if (pf) stageHalf(1, 3, 2 * t + 3); }

            if (q == 0) asm volatile("s_waitcnt lgkmcnt(8)" ::: "memory");
            __builtin_amdgcn_s_barrier();
            asm volatile("s_waitcnt lgkmcnt(0)" ::: "memory");
            __builtin_amdgcn_s_setprio(1);
#pragma unroll
            for (int m2 = 0; m2 < 2; ++m2)
#pragma unroll
                for (int nf = 0; nf < 4; ++nf)
#pragma unroll
                    for (int kk = 0; kk < 2; ++kk)
                        acc[q * 2 + m2][nf] = __builtin_amdgcn_mfma_f32_16x16x32_bf16(
                            aq[m2][kk], bq[nf][kk], acc[q * 2 + m2][nf], 0, 0, 0);
            __builtin_amdgcn_s_setprio(0);
            if (q == 3) {                                   // counted vmcnt, never mid-loop 0
                if (pf) asm volatile("s_waitcnt vmcnt(4)" ::: "memory");
                else    asm volatile("s_waitcnt vmcnt(0)" ::: "memory");
            }
            __builtin_amdgcn_s_barrier();
        }
    }

    // epilogue: restage C (bf16) through LDS for coalesced us8 stores
    u16* ct = (u16*)lds;                                    // 256x256 u16 = 128 KiB
#pragma unroll
    for (int mf = 0; mf < 8; ++mf)
#pragma unroll
        for (int nf = 0; nf < 4; ++nf) {
            const int row = wm * 128 + mf * 16 + ((lane >> 4) << 2);
            const int col = wn * 64 + nf * 16 + (lane & 15);
#pragma unroll
            for (int r = 0; r < 4; ++r)
                ct[(row + r) * 256 + col] = f2b(acc[mf][nf][r]);
        }
    __syncthreads();
#pragma unroll
    for (int it = 0; it < 16; ++it) {
        const int idx = it * 512 + tid;                     // 8192 us8 chunks
        const int row = idx >> 5;
        const int col = (idx & 31) * 8;
        *(us8*)(Cg + (arow0 + row) * (long)NCOL + bcol0 + col) = *(const us8*)(ct + row * 256 + col);
    }
}

// ---------------- kernel 2: wave-per-row LN + activations + cell update ----------------
static __device__ __forceinline__ void wave_meanrstd(float s, float ss, float& mean, float& rstd)
{
#pragma unroll
    for (int o = 1; o < 64; o <<= 1) { s += __shfl_xor(s, o); ss += __shfl_xor(ss, o); }
    mean = s * (1.f / 512.f);
    float var = (ss - 512.f * mean * mean) * (1.f / 511.f);
    rstd = 1.f / (sqrtf(fmaxf(var, 0.f)) + EPS);
}

__global__ __launch_bounds__(256)
void lstm_act(const u16* __restrict__ pre, const float* __restrict__ pc,
              const float* __restrict__ bf_, const float* __restrict__ bi_,
              const float* __restrict__ bo_, const float* __restrict__ bj_,
              const float* __restrict__ gf, const float* __restrict__ btf,
              const float* __restrict__ gi, const float* __restrict__ bti,
              const float* __restrict__ go, const float* __restrict__ bto,
              const float* __restrict__ gj, const float* __restrict__ btj,
              const float* __restrict__ gc, const float* __restrict__ btc,
              float* __restrict__ out_h, float* __restrict__ out_c)
{
    const long row  = (long)blockIdx.x * 4 + (threadIdx.x >> 6);
    const int  lane = threadIdx.x & 63;
    const int  c0   = lane * 8;

    const float* bs[4]  = { bf_, bi_, bo_, bj_ };
    const float* gs[4]  = { gf, gi, go, gj };
    const float* bts[4] = { btf, bti, bto, btj };

    float a[4][8];
#pragma unroll
    for (int g = 0; g < 4; ++g) {
        us8 pv = *(const us8*)(pre + row * NCOL + g * HDIM + c0);
        float4 bv0 = *(const float4*)(bs[g] + c0);
        float4 bv1 = *(const float4*)(bs[g] + c0 + 4);
        float bb[8] = { bv0.x, bv0.y, bv0.z, bv0.w, bv1.x, bv1.y, bv1.z, bv1.w };
        float y[8];
        float s = 0.f, ssum = 0.f;
#pragma unroll
        for (int e = 0; e < 8; ++e) {
            y[e] = b2f(pv[e]) + bb[e];
            s += y[e]; ssum += y[e] * y[e];
        }
        float mean, rstd;
        wave_meanrstd(s, ssum, mean, rstd);
        float4 g0 = *(const float4*)(gs[g] + c0);
        float4 g1 = *(const float4*)(gs[g] + c0 + 4);
        float4 t0 = *(const float4*)(bts[g] + c0);
        float4 t1 = *(const float4*)(bts[g] + c0 + 4);
        float gg[8] = { g0.x, g0.y, g0.z, g0.w, g1.x, g1.y, g1.z, g1.w };
        float tt[8] = { t0.x, t0.y, t0.z, t0.w, t1.x, t1.y, t1.z, t1.w };
#pragma unroll
        for (int e = 0; e < 8; ++e) {
            float z = (y[e] - mean) * rstd * gg[e] + tt[e];
            a[g][e] = (g == 3) ? tanhf(z) : 1.f / (1.f + expf(-z));
        }
    }

    float4 p0 = *(const float4*)(pc + row * HDIM + c0);
    float4 p1 = *(const float4*)(pc + row * HDIM + c0 + 4);
    float pcv[8] = { p0.x, p0.y, p0.z, p0.w, p1.x, p1.y, p1.z, p1.w };
    float cr[8];
    float s = 0.f, ssum = 0.f;
#pragma unroll
    for (int e = 0; e < 8; ++e) {
        cr[e] = a[0][e] * pcv[e] + fminf(1.f - a[0][e], a[1][e]) * a[3][e];
        s += cr[e]; ssum += cr[e] * cr[e];
    }
    float mean, rstd;
    wave_meanrstd(s, ssum, mean, rstd);
    float4 gc0 = *(const float4*)(gc + c0);
    float4 gc1 = *(const float4*)(gc + c0 + 4);
    float4 tc0 = *(const float4*)(btc + c0);
    float4 tc1 = *(const float4*)(btc + c0 + 4);
    float gg[8] = { gc0.x, gc0.y, gc0.z, gc0.w, gc1.x, gc1.y, gc1.z, gc1.w };
    float tt[8] = { tc0.x, tc0.y, tc0.z, tc0.w, tc1.x, tc1.y, tc1.z, tc1.w };
    float hv[8], cv[8];
#pragma unroll
    for (int e = 0; e < 8; ++e) {
        float cc = (cr[e] - mean) * rstd * gg[e] + tt[e];
        cv[e] = cc;
        hv[e] = a[2][e] * cc;
    }
    *(float4*)(out_h + row * HDIM + c0)     = make_float4(hv[0], hv[1], hv[2], hv[3]);
    *(float4*)(out_h + row * HDIM + c0 + 4) = make_float4(hv[4], hv[5], hv[6], hv[7]);
    *(float4*)(out_c + row * HDIM + c0)     = make_float4(cv[0], cv[1], cv[2], cv[3]);
    *(float4*)(out_c + row * HDIM + c0 + 4) = make_float4(cv[4], cv[5], cv[6], cv[7]);
}

// ---------------- fallback (only if ws too small): fp32 naive, no workspace ----------------
static __device__ __forceinline__ void ln_pair(
    float y0, float y1,
    const float* __restrict__ gam, const float* __restrict__ bet, int c0,
    float* red, int lane, int wid, float& o0, float& o1)
{
    float s = y0 + y1, ss = y0 * y0 + y1 * y1;
#pragma unroll
    for (int o = 32; o; o >>= 1) { s += __shfl_down(s, o); ss += __shfl_down(ss, o); }
    if (lane == 0) { red[wid * 2] = s; red[wid * 2 + 1] = ss; }
    __syncthreads();
    float S  = red[0] + red[2] + red[4] + red[6];
    float SS = red[1] + red[3] + red[5] + red[7];
    __syncthreads();
    float mean = S * (1.f / 512.f);
    float var  = (SS - 512.f * mean * mean) * (1.f / 511.f);
    float rstd = 1.f / (sqrtf(fmaxf(var, 0.f)) + EPS);
    o0 = (y0 - mean) * rstd * gam[c0]     + bet[c0];
    o1 = (y1 - mean) * rstd * gam[c0 + 1] + bet[c0 + 1];
}

__global__ __launch_bounds__(256)
void lstm_naive(const float* __restrict__ x, const float* __restrict__ ph, const float* __restrict__ pc,
                const float* __restrict__ Wf, const float* __restrict__ bf_,
                const float* __restrict__ Wi, const float* __restrict__ bi_,
                const float* __restrict__ Wo, const float* __restrict__ bo_,
                const float* __restrict__ Wj, const float* __restrict__ bj_,
                const float* __restrict__ gf, const float* __restrict__ btf,
                const float* __restrict__ gi, const float* __restrict__ bti,
                const float* __restrict__ go, const float* __restrict__ bto,
                const float* __restrict__ gj, const float* __restrict__ btj,
                const float* __restrict__ gc, const float* __restrict__ btc,
                float* __restrict__ out_h, float* __restrict__ out_c)
{
    __shared__ float comb[FAN];
    __shared__ float red[8];
    const int b = blockIdx.x, t = threadIdx.x;
    const int lane = t & 63, wid = t >> 6;
    for (int k = t; k < D_IN; k += 256) {
        comb[k]        = x[(long)b * D_IN + k];
        comb[D_IN + k] = ph[(long)b * HDIM + k];
    }
    __syncthreads();
    const int c0 = t * 2;
    const float* Ws[4]  = { Wf, Wi, Wo, Wj };
    const float* bs[4]  = { bf_, bi_, bo_, bj_ };
    const float* gs[4]  = { gf, gi, go, gj };
    const float* bts[4] = { btf, bti, bto, btj };
    float a[4][2];
#pragma unroll
    for (int g = 0; g < 4; ++g) {
        float y[2];
#pragma unroll
        for (int e = 0; e < 2; ++e) {
            const float4* w4 = (const float4*)(Ws[g] + (long)(c0 + e) * FAN);
            const float4* c4 = (const float4*)comb;
            float s = 0.f;
            for (int k = 0; k < FAN / 4; ++k) {
                float4 wv = w4[k], cv = c4[k];
                s += wv.x * cv.x + wv.y * cv.y + wv.z * cv.z + wv.w * cv.w;
            }
            y[e] = s + bs[g][c0 + e];
        }
        ln_pair(y[0], y[1], gs[g], bts[g], c0, red, lane, wid, a[g][0], a[g][1]);
        if (g == 3) { a[g][0] = tanhf(a[g][0]); a[g][1] = tanhf(a[g][1]); }
        else        { a[g][0] = 1.f / (1.f + expf(-a[g][0]));
                      a[g][1] = 1.f / (1.f + expf(-a[g][1])); }
    }
    float2 pcv = *(const float2*)(pc + (long)b * HDIM + c0);
    float f0 = a[0][0], i0 = a[1][0], o0 = a[2][0], j0 = a[3][0];
    float f1 = a[0][1], i1 = a[1][1], o1 = a[2][1], j1 = a[3][1];
    float cr0 = f0 * pcv.x + fminf(1.f - f0, i0) * j0;
    float cr1 = f1 * pcv.y + fminf(1.f - f1, i1) * j1;
    float cc0, cc1;
    ln_pair(cr0, cr1, gc, btc, c0, red, lane, wid, cc0, cc1);
    *(float2*)(out_h + (long)b * HDIM + c0) = make_float2(o0 * cc0, o1 * cc1);
    *(float2*)(out_c + (long)b * HDIM + c0) = make_float2(cc0, cc1);
}

// ---------------- launcher ----------------
extern "C" void kernel_launch(void* const* d_in, const int* in_sizes, int n_in,
                              void* d_out, int out_size, void* d_ws, size_t ws_size,
                              hipStream_t stream)
{
    const float* x   = (const float*)d_in[0];
    const float* ph  = (const float*)d_in[1];
    const float* pc  = (const float*)d_in[2];
    const float* Wf  = (const float*)d_in[3];
    const float* bf_ = (const float*)d_in[4];
    const float* Wi  = (const float*)d_in[5];
    const float* bi_ = (const float*)d_in[6];
    const float* Wo  = (const float*)d_in[7];
    const float* bo_ = (const float*)d_in[8];
    const float* Wj  = (const float*)d_in[9];
    const float* bj_ = (const float*)d_in[10];
    const float* gf  = (const float*)d_in[11];
    const float* btf = (const float*)d_in[12];
    const float* gi  = (const float*)d_in[13];
    const float* bti = (const float*)d_in[14];
    const float* go  = (const float*)d_in[15];
    const float* bto = (const float*)d_in[16];
    const float* gj  = (const float*)d_in[17];
    const float* btj = (const float*)d_in[18];
    const float* gc  = (const float*)d_in[19];
    const float* btc = (const float*)d_in[20];
    float* out_h = (float*)d_out;
    float* out_c = out_h + (size_t)B_ROWS * HDIM;

    const size_t combElems  = (size_t)B_ROWS * FAN;
    const size_t wElems     = (size_t)NCOL * FAN;
    const size_t fixedBytes = (combElems + wElems) * 2;

    long slabRows = 0;
    if (ws_size > fixedBytes) {
        size_t avail = ws_size - fixedBytes;
        slabRows = (long)(avail / ((size_t)NCOL * 2));
        slabRows &= ~255L;                                  // multiple of BM=256
        if (slabRows > B_ROWS) slabRows = B_ROWS;
    }

    if (slabRows >= 256) {
        u16* comb = (u16*)d_ws;
        u16* Wall = comb + combElems;
        u16* pre  = Wall + wElems;
        pack_combined<<<dim3((unsigned)((B_ROWS * (long)D_IN / 4 + 255) / 256)), dim3(256), 0, stream>>>(x, ph, comb);
        pack_w<<<dim3((unsigned)(((long)NCOL * FAN / 4 + 255) / 256)), dim3(256), 0, stream>>>(Wf, Wi, Wo, Wj, Wall);
        for (long r0 = 0; r0 < B_ROWS; r0 += slabRows) {
            long rows = B_ROWS - r0; if (rows > slabRows) rows = slabRows;
            gemm_gates<<<dim3((unsigned)((rows / BM) * (NCOL / BN))), dim3(512), 0, stream>>>(
                comb + r0 * FAN, Wall, pre);
            lstm_act<<<dim3((unsigned)(rows / 4)), dim3(256), 0, stream>>>(
                pre, pc + r0 * HDIM,
                bf_, bi_, bo_, bj_,
                gf, btf, gi, bti, go, bto, gj, btj, gc, btc,
                out_h + r0 * HDIM, out_c + r0 * HDIM);
        }
    } else {
        lstm_naive<<<dim3(B_ROWS), dim3(256), 0, stream>>>(
            x, ph, pc, Wf, bf_, Wi, bi_, Wo, bo_, Wj, bj_,
            gf, btf, gi, bti, go, bto, gj, btj, gc, btc, out_h, out_c);
    }
}